// Round 11
// baseline (1229.856 us; speedup 1.0000x reference)
//
#include <hip/hip_runtime.h>

typedef __attribute__((ext_vector_type(8))) short bf16x8;
typedef __attribute__((ext_vector_type(4))) float f32x4;
typedef __attribute__((ext_vector_type(4))) unsigned short us4;
typedef unsigned short u16;

#define MB (1024*1024)

#define WAITV(N) asm volatile("s_waitcnt vmcnt(" #N ")" ::: "memory")
#define WAITL0() asm volatile("s_waitcnt lgkmcnt(0)" ::: "memory")
#define BAR()    __builtin_amdgcn_s_barrier()
#define SCHEDB() __builtin_amdgcn_sched_barrier(0)

// diagnostic repeats (idempotent)
#define REP_CTX 5
#define REP_PW  3

__device__ __forceinline__ u16 f2bf(float f) {
    unsigned u = __float_as_uint(f);
    unsigned r = (u + 0x7fffu + ((u >> 16) & 1u)) >> 16;
    return (u16)r;
}

__device__ __forceinline__ unsigned cvtpk(float a, float b) {
    unsigned r;
    asm("v_cvt_pk_bf16_f32 %0, %1, %2" : "=v"(r) : "v"(a), "v"(b));
    return r;
}

__device__ __forceinline__ f32x4 mfma16(bf16x8 a, bf16x8 b, f32x4 c) {
    return __builtin_amdgcn_mfma_f32_16x16x32_bf16(a, b, c, 0, 0, 0);
}

__device__ __forceinline__ void gload16(const void* g, void* l) {
    __builtin_amdgcn_global_load_lds(
        (__attribute__((address_space(1))) void*)(unsigned long long)g,
        (__attribute__((address_space(3))) void*)l, 16, 0, 0);
}

// ---------------- x -> bf16 ----------------
__global__ __launch_bounds__(256) void k_cvtx(const float* __restrict__ x, u16* __restrict__ xb) {
    const long long i = (long long)blockIdx.x * 256 + threadIdx.x;
    const float4* xp = (const float4*)x;
    float4 a = xp[i*2], b = xp[i*2+1];
    bf16x8 o;
    o[0]=(short)f2bf(a.x); o[1]=(short)f2bf(a.y); o[2]=(short)f2bf(a.z); o[3]=(short)f2bf(a.w);
    o[4]=(short)f2bf(b.x); o[5]=(short)f2bf(b.y); o[6]=(short)f2bf(b.z); o[7]=(short)f2bf(b.w);
    *(bf16x8*)&xb[i*8] = o;
}

// ---------------- W (K x N) -> Wt bf16 (N x K) ----------------
__global__ __launch_bounds__(256) void k_wtcvt(const float* __restrict__ W0, const float* __restrict__ W1,
                                               const float* __restrict__ W2, const float* __restrict__ W3,
                                               u16* __restrict__ wt) {
    __shared__ float tl[32][33];
    const int t = threadIdx.x, z = blockIdx.z;
    const float* W = (z==0)?W0:(z==1)?W1:(z==2)?W2:W3;
    const int k0 = blockIdx.x*32, n0 = blockIdx.y*32;
    const int r = t >> 3, c4 = (t & 7) * 4;
    float4 v = *(const float4*)&W[(long long)(k0+r)*1024 + n0 + c4];
    tl[r][c4] = v.x; tl[r][c4+1] = v.y; tl[r][c4+2] = v.z; tl[r][c4+3] = v.w;
    __syncthreads();
    us4 ov;
    ov[0] = f2bf(tl[c4+0][r]); ov[1] = f2bf(tl[c4+1][r]);
    ov[2] = f2bf(tl[c4+2][r]); ov[3] = f2bf(tl[c4+3][r]);
    *(us4*)&wt[((long long)z << 20) + (long long)(n0+r)*1024 + k0 + c4] = ov;
}

// ---------------- geo chain ----------------
__global__ __launch_bounds__(1024) void k_geo1(const float* __restrict__ geo, const float* __restrict__ W1,
                                               const float* __restrict__ b1, const float* __restrict__ lng,
                                               const float* __restrict__ lnb, float* __restrict__ hr) {
    const int b = blockIdx.x, j = threadIdx.x;
    float acc = b1[j];
    #pragma unroll 8
    for (int g = 0; g < 32; ++g) acc += geo[b*32+g] * W1[(long long)g*1024 + j];
    float s1 = acc, s2 = acc*acc;
    #pragma unroll
    for (int m = 1; m < 64; m <<= 1) { s1 += __shfl_xor(s1, m); s2 += __shfl_xor(s2, m); }
    __shared__ float r1[16], r2[16];
    __shared__ float mu_s, rv_s;
    const int wid = j >> 6, lid = j & 63;
    if (lid == 0) { r1[wid] = s1; r2[wid] = s2; }
    __syncthreads();
    if (j == 0) {
        float S1 = 0.f, S2 = 0.f;
        for (int i = 0; i < 16; ++i) { S1 += r1[i]; S2 += r2[i]; }
        float mu = S1 / 1024.f;
        float var = S2 / 1024.f - mu*mu;
        mu_s = mu; rv_s = rsqrtf(var + 1e-5f);
    }
    __syncthreads();
    float hv = (acc - mu_s) * rv_s * lng[j] + lnb[j];
    hr[b*1024 + j] = fmaxf(hv, 0.f);
}

__global__ __launch_bounds__(256) void k_geo2(const float* __restrict__ hr, const float* __restrict__ W2,
                                              const float* __restrict__ b2, float* __restrict__ ge) {
    const int b = blockIdx.x >> 4, jc = blockIdx.x & 15;
    const int t = threadIdx.x;
    __shared__ float hs[1024];
    __shared__ float parts[4][64];
    #pragma unroll
    for (int i = 0; i < 4; ++i) hs[t*4 + i] = hr[b*1024 + t*4 + i];
    __syncthreads();
    const int j = jc*64 + (t & 63), dq = t >> 6;
    float acc = 0.f;
    #pragma unroll 16
    for (int dd = 0; dd < 256; ++dd) {
        const int d = dq*256 + dd;
        acc += hs[d] * W2[(long long)d*1024 + j];
    }
    parts[dq][t & 63] = acc;
    __syncthreads();
    if (t < 64) {
        const int jj = jc*64 + t;
        ge[b*1024 + jj] = b2[jj] + parts[0][t] + parts[1][t] + parts[2][t] + parts[3][t];
    }
}

__global__ __launch_bounds__(1024) void k_geo3(const float* __restrict__ ge, const float* __restrict__ gmW,
                                               const float* __restrict__ gmb, float* __restrict__ qs) {
    const int t = threadIdx.x;
    const int hh = t & 15, b = (t >> 4) & 3, dq = t >> 6;
    __shared__ float parts[16][64];
    float part = 0.f;
    #pragma unroll 16
    for (int dd = 0; dd < 64; ++dd) {
        const int d = dq*64 + dd;
        part += ge[b*1024 + d] * gmW[d*16 + hh];
    }
    parts[dq][b*16 + hh] = part;
    __syncthreads();
    if (t < 64) {
        float s = gmb[t & 15];
        #pragma unroll
        for (int k = 0; k < 16; ++k) s += parts[k][t];
        qs[t] = 0.125f * (1.f + 1.f/(1.f + __expf(-s)));
    }
}

// ---------------- QKV projection GEMM ----------------
__global__ __launch_bounds__(256) void k_qkv_gemm(const u16* __restrict__ xb, const u16* __restrict__ wtq,
                                                  const float* __restrict__ bq, const float* __restrict__ bk,
                                                  const float* __restrict__ bv, u16* __restrict__ outq) {
    __shared__ u16 lA[128*64];
    __shared__ u16 lB[128*64];
    const int t = threadIdx.x, z = blockIdx.z;
    const int m0 = blockIdx.y * 128, n0 = blockIdx.x * 128;
    const u16* wt = wtq + (long long)z * (1024*1024);
    const float* bias = (z==0) ? bq : (z==1) ? bk : bv;
    u16* out = outq + (long long)z * 8388608;
    const int w = t >> 6, l = t & 63, lm = l & 15, lg = l >> 4;
    const int wr = (w >> 1) * 64, wc = (w & 1) * 64;
    f32x4 acc[4][4] = {};
    const char* gA = (const char*)xb + (long long)(m0 + (t>>3))*2048 + (t&7)*16;
    const char* gB = (const char*)wt + (long long)(n0 + (t>>3))*2048 + (t&7)*16;
    char* lAp = (char*)lA + t*16;
    char* lBp = (char*)lB + t*16;
    for (int k0 = 0; k0 < 1024; k0 += 64) {
        #pragma unroll
        for (int i = 0; i < 4; ++i) {
            gload16(gA + (long long)i*32*2048, lAp + i*4096);
            gload16(gB + (long long)i*32*2048, lBp + i*4096);
        }
        gA += 128; gB += 128;
        __syncthreads();
        #pragma unroll
        for (int kk = 0; kk < 2; ++kk) {
            bf16x8 af[4], bfr[4];
            #pragma unroll
            for (int mi = 0; mi < 4; ++mi)
                af[mi] = *(const bf16x8*)((const char*)lA + (wr + mi*16 + lm)*128 + kk*64 + lg*16);
            #pragma unroll
            for (int ni = 0; ni < 4; ++ni)
                bfr[ni] = *(const bf16x8*)((const char*)lB + (wc + ni*16 + lm)*128 + kk*64 + lg*16);
            #pragma unroll
            for (int mi = 0; mi < 4; ++mi)
                #pragma unroll
                for (int ni = 0; ni < 4; ++ni)
                    acc[mi][ni] = mfma16(bfr[ni], af[mi], acc[mi][ni]);
        }
        __syncthreads();
    }
    #pragma unroll
    for (int mi = 0; mi < 4; ++mi) {
        const int m = m0 + wr + mi*16 + lm;
        const int b = m >> 11, s = m & 2047;
        #pragma unroll
        for (int ni = 0; ni < 4; ++ni) {
            const int nb = n0 + wc + ni*16 + lg*4;
            const float4 bn4 = *(const float4*)&bias[nb];
            const int hh = nb >> 6, d = nb & 63;
            uint2 pk;
            pk.x = cvtpk(acc[mi][ni][0] + bn4.x, acc[mi][ni][1] + bn4.y);
            pk.y = cvtpk(acc[mi][ni][2] + bn4.z, acc[mi][ni][3] + bn4.w);
            *(uint2*)&out[(((long long)b*16 + hh)*2048 + s)*64 + d] = pk;
        }
    }
}

// ---------------- V [bh][s][d] -> Vt [bh][d][s] ----------------
__global__ __launch_bounds__(256) void k_vtrans(const u16* __restrict__ vb, u16* __restrict__ vt) {
    __shared__ u16 tl[64][40];
    const int t = threadIdx.x;
    const int bh = blockIdx.z, s0 = blockIdx.y*64, d0 = blockIdx.x*32;
    const u16* vsrc = vb + (long long)bh*2048*64;
    {
        const int sl = t >> 2, dg = t & 3;
        bf16x8 v = *(const bf16x8*)&vsrc[(long long)(s0+sl)*64 + d0 + dg*8];
        *(bf16x8*)&tl[sl][dg*8] = v;
    }
    __syncthreads();
    {
        const int dl = t >> 3, sg = t & 7;
        bf16x8 o;
        #pragma unroll
        for (int j = 0; j < 8; ++j) o[j] = (short)tl[sg*8+j][dl];
        *(bf16x8*)&vt[((long long)bh*64 + d0+dl)*2048 + s0 + sg*8] = o;
    }
}

// ---------------- attention pass 1: ctx + invl (x REP_CTX for rocprof) ----------------
__global__ __launch_bounds__(512, 4) void k_attn_ctx(const u16* __restrict__ Qb, const u16* __restrict__ Kb,
                                                     const u16* __restrict__ Vt, const float* __restrict__ qsv,
                                                     float* __restrict__ invg, u16* __restrict__ ctxb) {
    __shared__ char lds[81920];

    const int nl = blockIdx.x;
    const int ob = (nl & 7)*64 + (nl >> 3);
    const int bh = ob >> 3, qt = ob & 7;
    const int t = threadIdx.x, w = t >> 6, l = t & 63, lm = l & 15, lg = l >> 4;
    const int q0 = qt * 256;
    const float qs = qsv[bh];

    const char* KB = (const char*)Kb + (long long)bh * 262144;
    const char* VB = (const char*)Vt + (long long)bh * 262144;

    bf16x8 qf[2][2];
    {
        const char* QB = (const char*)Qb + (long long)bh * 262144;
        #pragma unroll
        for (int ms = 0; ms < 2; ++ms)
            #pragma unroll
            for (int kc = 0; kc < 2; ++kc)
                qf[ms][kc] = *(const bf16x8*)(QB + (long long)(q0 + w*32 + ms*16 + lm)*128 + kc*64 + lg*16);
    }

    const int off = t*16;
    const int row = off >> 7, cbyt = off & 127;
    const int offA = off;
    const int srcK = row*128  + (cbyt ^ ((row & 7) << 4));
    const int srcV = row*4096 + (cbyt ^ ((row & 7) << 4));

    char* lP = lds + 49152;

    #pragma unroll 1
    for (int rep = 0; rep < REP_CTX; ++rep) {
        WAITV(0); BAR(); SCHEDB();   // drain residual gloads before LDS reuse

        float lsum[2] = {0.f, 0.f};
        f32x4 cacc[2][4] = {};

        gload16(KB + srcK, lds + offA);
        gload16(VB + srcV, lds + 24576 + offA);
        gload16(KB + 8192 + srcK, lds + 8192 + offA);
        gload16(VB + 128 + srcV, lds + 24576 + 8192 + offA);
        SCHEDB();
        WAITV(2); BAR(); SCHEDB();

        int cb_ = 0, sb_ = 2;
        for (int kt = 0; kt < 32; ++kt) {
            const int ktn = (kt < 30) ? kt + 2 : 31;
            gload16(KB + (long long)ktn*8192 + srcK, lds + sb_*8192 + offA);
            gload16(VB + (long long)ktn*128 + srcV, lds + 24576 + sb_*8192 + offA);
            SCHEDB();

            const char* kb = lds + cb_*8192;
            #pragma unroll
            for (int ns = 0; ns < 4; ++ns) {
                const int rowb = ns*16 + lm;
                const int tag = (rowb & 7) << 4;
                bf16x8 kf0 = *(const bf16x8*)(kb + rowb*128 + ((lg*16) ^ tag));
                bf16x8 kf1 = *(const bf16x8*)(kb + rowb*128 + ((64 + lg*16) ^ tag));
                #pragma unroll
                for (int ms = 0; ms < 2; ++ms) {
                    f32x4 a = {};
                    a = mfma16(kf0, qf[ms][0], a);
                    a = mfma16(kf1, qf[ms][1], a);
                    const float p0 = __expf(a[0]*qs);
                    const float p1 = __expf(a[1]*qs);
                    const float p2 = __expf(a[2]*qs);
                    const float p3 = __expf(a[3]*qs);
                    lsum[ms] += (p0 + p1) + (p2 + p3);
                    const int prow = w*32 + ms*16 + lm;
                    const int ptag = (prow & 7) << 4;
                    uint2 pk; pk.x = cvtpk(p0, p1); pk.y = cvtpk(p2, p3);
                    *(uint2*)(lP + prow*128 + ((32*ns + 8*lg) ^ ptag)) = pk;
                }
            }
            WAITL0(); SCHEDB();

            const char* vb = lds + 24576 + cb_*8192;
            #pragma unroll
            for (int ks = 0; ks < 2; ++ks) {
                bf16x8 pa[2];
                #pragma unroll
                for (int ms = 0; ms < 2; ++ms) {
                    const int prow = w*32 + ms*16 + lm;
                    pa[ms] = *(const bf16x8*)(lP + prow*128 + ((ks*64 + lg*16) ^ ((prow & 7) << 4)));
                }
                #pragma unroll
                for (int dn = 0; dn < 4; ++dn) {
                    const int rv = dn*16 + lm;
                    bf16x8 vf = *(const bf16x8*)(vb + rv*128 + ((ks*64 + lg*16) ^ ((rv & 7) << 4)));
                    cacc[0][dn] = mfma16(pa[0], vf, cacc[0][dn]);
                    cacc[1][dn] = mfma16(pa[1], vf, cacc[1][dn]);
                }
            }
            WAITV(2); BAR(); SCHEDB();
            cb_ = (cb_ == 2) ? 0 : cb_ + 1;
            sb_ = (sb_ == 2) ? 0 : sb_ + 1;
        }

        float invl[2];
        #pragma unroll
        for (int ms = 0; ms < 2; ++ms) {
            float v = lsum[ms];
            v += __shfl_xor(v, 16);
            v += __shfl_xor(v, 32);
            invl[ms] = 1.f / v;
        }
        if (lg == 0) {
            invg[bh*2048 + q0 + w*32 + lm]      = invl[0];
            invg[bh*2048 + q0 + w*32 + 16 + lm] = invl[1];
        }
        float* fs = (float*)(lP + w*4096);
        if (lg == 0) { fs[lm] = invl[0]; fs[16 + lm] = invl[1]; }
        WAITL0(); SCHEDB();
        f32x4 iv[2];
        iv[0] = *(const f32x4*)&fs[lg*4];
        iv[1] = *(const f32x4*)&fs[16 + lg*4];

        const int b = bh >> 4, hh = bh & 15;
        #pragma unroll
        for (int ms = 0; ms < 2; ++ms)
            #pragma unroll
            for (int dn = 0; dn < 4; ++dn)
                #pragma unroll
                for (int r = 0; r < 4; ++r) {
                    const int q = q0 + w*32 + ms*16 + lg*4 + r;
                    ctxb[(((long long)b*2048 + q)*16 + hh)*64 + dn*16 + lm] = f2bf(cacc[ms][dn][r] * iv[ms][r]);
                }
        BAR(); SCHEDB();   // fs reads done before next rep's lP writes
    }
}

// ---------------- attention pass 2 v3 (x REP_PW for rocprof) ----------------
__global__ __launch_bounds__(256, 2) void k_pwrite(const u16* __restrict__ Qb, const u16* __restrict__ Kb,
                                                   const float* __restrict__ qsv, const float* __restrict__ invg,
                                                   float* __restrict__ attn_out) {
    __shared__ char lds[81920];

    const int nl = blockIdx.x;
    const int ob = (nl & 7)*512 + (nl >> 3);   // XCD-chunked (4096 % 8 == 0)
    const int bh = ob >> 6, qt = ob & 63;
    const int t = threadIdx.x, w = t >> 6, l = t & 63, lm = l & 15, lg = l >> 4;
    const int q0 = qt * 32;
    const int qg = w & 1, kq = w >> 1;
    const float qs = qsv[bh];

    const char* KB = (const char*)Kb + (long long)bh * 262144;

    bf16x8 qf[2];
    {
        const char* QB = (const char*)Qb + (long long)bh * 262144;
        #pragma unroll
        for (int kc = 0; kc < 2; ++kc)
            qf[kc] = *(const bf16x8*)(QB + (long long)(q0 + qg*16 + lm)*128 + kc*64 + lg*16);
    }
    const float invq = invg[bh*2048 + q0 + qg*16 + lm];

    int offA[2], srcK[2];
    #pragma unroll
    for (int i = 0; i < 2; ++i) {
        const int off = i*4096 + t*16;
        const int row = off >> 7, cbyt = off & 127;
        offA[i] = off;
        srcK[i] = row*128 + (cbyt ^ ((row & 7) << 4));
    }

    char* lP = lds + 49152;

    #pragma unroll 1
    for (int rep = 0; rep < REP_PW; ++rep) {
        WAITV(0); BAR(); SCHEDB();

        #pragma unroll
        for (int tt = 0; tt < 5; ++tt)
            #pragma unroll
            for (int i = 0; i < 2; ++i)
                gload16(KB + (long long)tt*8192 + srcK[i], lds + tt*8192 + offA[i]);
        SCHEDB();

        for (int kt = 0; kt < 32; ++kt) {
            if (kt < 4)              { WAITV(8); }
            else if (kt == 4)        { WAITV(16); }
            else if ((kt & 3) == 0)  { WAITV(24); }
            else                     { WAITV(16); }
            BAR(); SCHEDB();

            {
                const int ktn = (kt + 5 < 32) ? kt + 5 : 31;
                char* dst = lds + ((kt + 5) % 6)*8192;
                #pragma unroll
                for (int i = 0; i < 2; ++i)
                    gload16(KB + (long long)ktn*8192 + srcK[i], dst + offA[i]);
            }
            SCHEDB();

            const char* kb = lds + (kt % 6)*8192;
            #pragma unroll
            for (int ns = 0; ns < 2; ++ns) {
                const int rowb = kq*32 + ns*16 + lm;
                const int tag = (lm & 7) << 4;
                bf16x8 kf0 = *(const bf16x8*)(kb + rowb*128 + ((lg*16) ^ tag));
                bf16x8 kf1 = *(const bf16x8*)(kb + rowb*128 + ((64 + lg*16) ^ tag));
                f32x4 a = {};
                a = mfma16(kf0, qf[0], a);
                a = mfma16(kf1, qf[1], a);
                f32x4 pv4;
                pv4[0] = __expf(a[0]*qs) * invq;
                pv4[1] = __expf(a[1]*qs) * invq;
                pv4[2] = __expf(a[2]*qs) * invq;
                pv4[3] = __expf(a[3]*qs) * invq;
                const int prow = qg*16 + lm;
                const int kwb = ((kt & 3) << 8) + (kq << 7) + (ns << 6) + (lg << 4);
                *(f32x4*)(lP + prow*1024 + (kwb ^ (lm << 4))) = pv4;
            }

            if ((kt & 3) == 3) {
                const int win = kt >> 2;
                WAITL0(); BAR(); SCHEDB();
                const int r0 = w*8;
                #pragma unroll
                for (int r = 0; r < 8; ++r) {
                    const int rr = r0 + r;
                    f32x4 v = *(const f32x4*)(lP + rr*1024 + ((l*16) ^ ((rr & 15) << 4)));
                    *(f32x4*)(attn_out + ((long long)(bh*2048 + q0 + rr))*2048 + win*256 + l*4) = v;
                }
                SCHEDB();
            }
        }
    }
}

// ---------------- output projection ----------------
__global__ __launch_bounds__(256) void k_o_gemm(const u16* __restrict__ ab, const u16* __restrict__ wt,
                                                const float* __restrict__ bo, float* __restrict__ outf) {
    __shared__ u16 lA[128*64];
    __shared__ u16 lB[128*64];
    const int t = threadIdx.x;
    const int m0 = blockIdx.y * 128, n0 = blockIdx.x * 128;
    const int w = t >> 6, l = t & 63, lm = l & 15, lg = l >> 4;
    const int wr = (w >> 1) * 64, wc = (w & 1) * 64;
    f32x4 acc[4][4] = {};
    const char* gA = (const char*)ab + (long long)(m0 + (t>>3))*2048 + (t&7)*16;
    const char* gB = (const char*)wt + (long long)(n0 + (t>>3))*2048 + (t&7)*16;
    char* lAp = (char*)lA + t*16;
    char* lBp = (char*)lB + t*16;
    for (int k0 = 0; k0 < 1024; k0 += 64) {
        #pragma unroll
        for (int i = 0; i < 4; ++i) {
            gload16(gA + (long long)i*32*2048, lAp + i*4096);
            gload16(gB + (long long)i*32*2048, lBp + i*4096);
        }
        gA += 128; gB += 128;
        __syncthreads();
        #pragma unroll
        for (int kk = 0; kk < 2; ++kk) {
            bf16x8 af[4], bfr[4];
            #pragma unroll
            for (int mi = 0; mi < 4; ++mi)
                af[mi] = *(const bf16x8*)((const char*)lA + (wr + mi*16 + lm)*128 + kk*64 + lg*16);
            #pragma unroll
            for (int ni = 0; ni < 4; ++ni)
                bfr[ni] = *(const bf16x8*)((const char*)lB + (wc + ni*16 + lm)*128 + kk*64 + lg*16);
            #pragma unroll
            for (int mi = 0; mi < 4; ++mi)
                #pragma unroll
                for (int ni = 0; ni < 4; ++ni)
                    acc[mi][ni] = mfma16(bfr[ni], af[mi], acc[mi][ni]);
        }
        __syncthreads();
    }
    #pragma unroll
    for (int mi = 0; mi < 4; ++mi) {
        const int m = m0 + wr + mi*16 + lm;
        #pragma unroll
        for (int ni = 0; ni < 4; ++ni) {
            const int nb = n0 + wc + ni*16 + lg*4;
            const float4 bn4 = *(const float4*)&bo[nb];
            f32x4 v = acc[mi][ni];
            v[0] += bn4.x; v[1] += bn4.y; v[2] += bn4.z; v[3] += bn4.w;
            *(f32x4*)&outf[(long long)m*1024 + nb] = v;
        }
    }
}

extern "C" void kernel_launch(void* const* d_in, const int* in_sizes, int n_in,
                              void* d_out, int out_size, void* d_ws, size_t ws_size,
                              hipStream_t stream) {
    const float* x    = (const float*)d_in[0];
    const float* geo  = (const float*)d_in[1];
    const float* Wq   = (const float*)d_in[2];
    const float* bq   = (const float*)d_in[3];
    const float* Wk   = (const float*)d_in[4];
    const float* bk   = (const float*)d_in[5];
    const float* Wv   = (const float*)d_in[6];
    const float* bv   = (const float*)d_in[7];
    const float* Wo   = (const float*)d_in[8];
    const float* bo   = (const float*)d_in[9];
    const float* geW1 = (const float*)d_in[10];
    const float* geb1 = (const float*)d_in[11];
    const float* lng  = (const float*)d_in[12];
    const float* lnb  = (const float*)d_in[13];
    const float* geW2 = (const float*)d_in[14];
    const float* geb2 = (const float*)d_in[15];
    const float* gmW  = (const float*)d_in[16];
    const float* gmb  = (const float*)d_in[17];

    char* ws = (char*)d_ws;
    u16* xb   = (u16*)(ws + 0);                 // 16 MB (dead after k_qkv_gemm)
    u16* wt   = (u16*)(ws + 16*(size_t)MB);     // 4 x 2 MB
    u16* qkv  = (u16*)(ws + 24*(size_t)MB);     // Q,K,V each 16 MB
    u16* Qb   = qkv;
    u16* Kb   = (u16*)(ws + 40*(size_t)MB);
    u16* Vb   = (u16*)(ws + 56*(size_t)MB);
    u16* Vt   = (u16*)(ws + 72*(size_t)MB);
    u16* ctx  = Vb;                              // reuse V-raw after transpose
    float* qsb= (float*)(ws + 88*(size_t)MB);
    float* hr = (float*)(ws + 88*(size_t)MB + 4096);
    float* ge = (float*)(ws + 88*(size_t)MB + 65536);
    float* invg = (float*)(ws + 0);              // reuse xb region (dead by k_attn_ctx)

    float* outf = (float*)d_out;
    float* attn = outf + 8388608;

    hipLaunchKernelGGL(k_cvtx,     dim3(4096),      dim3(256),  0, stream, x, xb);
    hipLaunchKernelGGL(k_wtcvt,    dim3(32,32,4),   dim3(256),  0, stream, Wq, Wk, Wv, Wo, wt);
    hipLaunchKernelGGL(k_geo1,     dim3(4),         dim3(1024), 0, stream, geo, geW1, geb1, lng, lnb, hr);
    hipLaunchKernelGGL(k_geo2,     dim3(64),        dim3(256),  0, stream, hr, geW2, geb2, ge);
    hipLaunchKernelGGL(k_geo3,     dim3(1),         dim3(1024), 0, stream, ge, gmW, gmb, qsb);
    hipLaunchKernelGGL(k_qkv_gemm, dim3(8,64,3),    dim3(256),  0, stream, xb, wt, bq, bk, bv, qkv);
    hipLaunchKernelGGL(k_vtrans,   dim3(2,32,64),   dim3(256),  0, stream, Vb, Vt);
    hipLaunchKernelGGL(k_attn_ctx, dim3(512),       dim3(512),  0, stream, Qb, Kb, Vt, qsb, invg, ctx);
    hipLaunchKernelGGL(k_pwrite,   dim3(4096),      dim3(256),  0, stream, Qb, Kb, qsb, invg, attn);
    hipLaunchKernelGGL(k_o_gemm,   dim3(8,64),      dim3(256),  0, stream, ctx, wt + 3*1048576, bo, outf);
}

// Round 12
// 548.965 us; speedup vs baseline: 2.2403x; 2.2403x over previous
//
#include <hip/hip_runtime.h>

typedef __attribute__((ext_vector_type(8))) short bf16x8;
typedef __attribute__((ext_vector_type(4))) float f32x4;
typedef __attribute__((ext_vector_type(4))) unsigned short us4;
typedef unsigned short u16;

#define MB (1024*1024)

#define WAITV(N) asm volatile("s_waitcnt vmcnt(" #N ")" ::: "memory")
#define WAITL0() asm volatile("s_waitcnt lgkmcnt(0)" ::: "memory")
#define BAR()    __builtin_amdgcn_s_barrier()
#define SCHEDB() __builtin_amdgcn_sched_barrier(0)

__device__ __forceinline__ u16 f2bf(float f) {
    unsigned u = __float_as_uint(f);
    unsigned r = (u + 0x7fffu + ((u >> 16) & 1u)) >> 16;
    return (u16)r;
}

__device__ __forceinline__ unsigned cvtpk(float a, float b) {
    unsigned r;
    asm("v_cvt_pk_bf16_f32 %0, %1, %2" : "=v"(r) : "v"(a), "v"(b));
    return r;
}

__device__ __forceinline__ f32x4 mfma16(bf16x8 a, bf16x8 b, f32x4 c) {
    return __builtin_amdgcn_mfma_f32_16x16x32_bf16(a, b, c, 0, 0, 0);
}

__device__ __forceinline__ void gload16(const void* g, void* l) {
    __builtin_amdgcn_global_load_lds(
        (__attribute__((address_space(1))) void*)(unsigned long long)g,
        (__attribute__((address_space(3))) void*)l, 16, 0, 0);
}

// ---------------- x -> bf16 ----------------
__global__ __launch_bounds__(256) void k_cvtx(const float* __restrict__ x, u16* __restrict__ xb) {
    const long long i = (long long)blockIdx.x * 256 + threadIdx.x;
    const float4* xp = (const float4*)x;
    float4 a = xp[i*2], b = xp[i*2+1];
    bf16x8 o;
    o[0]=(short)f2bf(a.x); o[1]=(short)f2bf(a.y); o[2]=(short)f2bf(a.z); o[3]=(short)f2bf(a.w);
    o[4]=(short)f2bf(b.x); o[5]=(short)f2bf(b.y); o[6]=(short)f2bf(b.z); o[7]=(short)f2bf(b.w);
    *(bf16x8*)&xb[i*8] = o;
}

// ---------------- W (K x N) -> Wt bf16 (N x K) ----------------
__global__ __launch_bounds__(256) void k_wtcvt(const float* __restrict__ W0, const float* __restrict__ W1,
                                               const float* __restrict__ W2, const float* __restrict__ W3,
                                               u16* __restrict__ wt) {
    __shared__ float tl[32][33];
    const int t = threadIdx.x, z = blockIdx.z;
    const float* W = (z==0)?W0:(z==1)?W1:(z==2)?W2:W3;
    const int k0 = blockIdx.x*32, n0 = blockIdx.y*32;
    const int r = t >> 3, c4 = (t & 7) * 4;
    float4 v = *(const float4*)&W[(long long)(k0+r)*1024 + n0 + c4];
    tl[r][c4] = v.x; tl[r][c4+1] = v.y; tl[r][c4+2] = v.z; tl[r][c4+3] = v.w;
    __syncthreads();
    us4 ov;
    ov[0] = f2bf(tl[c4+0][r]); ov[1] = f2bf(tl[c4+1][r]);
    ov[2] = f2bf(tl[c4+2][r]); ov[3] = f2bf(tl[c4+3][r]);
    *(us4*)&wt[((long long)z << 20) + (long long)(n0+r)*1024 + k0 + c4] = ov;
}

// ---------------- geo chain ----------------
__global__ __launch_bounds__(1024) void k_geo1(const float* __restrict__ geo, const float* __restrict__ W1,
                                               const float* __restrict__ b1, const float* __restrict__ lng,
                                               const float* __restrict__ lnb, float* __restrict__ hr) {
    const int b = blockIdx.x, j = threadIdx.x;
    float acc = b1[j];
    #pragma unroll 8
    for (int g = 0; g < 32; ++g) acc += geo[b*32+g] * W1[(long long)g*1024 + j];
    float s1 = acc, s2 = acc*acc;
    #pragma unroll
    for (int m = 1; m < 64; m <<= 1) { s1 += __shfl_xor(s1, m); s2 += __shfl_xor(s2, m); }
    __shared__ float r1[16], r2[16];
    __shared__ float mu_s, rv_s;
    const int wid = j >> 6, lid = j & 63;
    if (lid == 0) { r1[wid] = s1; r2[wid] = s2; }
    __syncthreads();
    if (j == 0) {
        float S1 = 0.f, S2 = 0.f;
        for (int i = 0; i < 16; ++i) { S1 += r1[i]; S2 += r2[i]; }
        float mu = S1 / 1024.f;
        float var = S2 / 1024.f - mu*mu;
        mu_s = mu; rv_s = rsqrtf(var + 1e-5f);
    }
    __syncthreads();
    float hv = (acc - mu_s) * rv_s * lng[j] + lnb[j];
    hr[b*1024 + j] = fmaxf(hv, 0.f);
}

__global__ __launch_bounds__(256) void k_geo2(const float* __restrict__ hr, const float* __restrict__ W2,
                                              const float* __restrict__ b2, float* __restrict__ ge) {
    const int b = blockIdx.x >> 4, jc = blockIdx.x & 15;
    const int t = threadIdx.x;
    __shared__ float hs[1024];
    __shared__ float parts[4][64];
    #pragma unroll
    for (int i = 0; i < 4; ++i) hs[t*4 + i] = hr[b*1024 + t*4 + i];
    __syncthreads();
    const int j = jc*64 + (t & 63), dq = t >> 6;
    float acc = 0.f;
    #pragma unroll 16
    for (int dd = 0; dd < 256; ++dd) {
        const int d = dq*256 + dd;
        acc += hs[d] * W2[(long long)d*1024 + j];
    }
    parts[dq][t & 63] = acc;
    __syncthreads();
    if (t < 64) {
        const int jj = jc*64 + t;
        ge[b*1024 + jj] = b2[jj] + parts[0][t] + parts[1][t] + parts[2][t] + parts[3][t];
    }
}

__global__ __launch_bounds__(1024) void k_geo3(const float* __restrict__ ge, const float* __restrict__ gmW,
                                               const float* __restrict__ gmb, float* __restrict__ qs) {
    const int t = threadIdx.x;
    const int hh = t & 15, b = (t >> 4) & 3, dq = t >> 6;
    __shared__ float parts[16][64];
    float part = 0.f;
    #pragma unroll 16
    for (int dd = 0; dd < 64; ++dd) {
        const int d = dq*64 + dd;
        part += ge[b*1024 + d] * gmW[d*16 + hh];
    }
    parts[dq][b*16 + hh] = part;
    __syncthreads();
    if (t < 64) {
        float s = gmb[t & 15];
        #pragma unroll
        for (int k = 0; k < 16; ++k) s += parts[k][t];
        qs[t] = 0.125f * (1.f + 1.f/(1.f + __expf(-s)));
    }
}

// ---------------- QKV projection GEMM ----------------
__global__ __launch_bounds__(256) void k_qkv_gemm(const u16* __restrict__ xb, const u16* __restrict__ wtq,
                                                  const float* __restrict__ bq, const float* __restrict__ bk,
                                                  const float* __restrict__ bv, u16* __restrict__ outq) {
    __shared__ u16 lA[128*64];
    __shared__ u16 lB[128*64];
    const int t = threadIdx.x, z = blockIdx.z;
    const int m0 = blockIdx.y * 128, n0 = blockIdx.x * 128;
    const u16* wt = wtq + (long long)z * (1024*1024);
    const float* bias = (z==0) ? bq : (z==1) ? bk : bv;
    u16* out = outq + (long long)z * 8388608;
    const int w = t >> 6, l = t & 63, lm = l & 15, lg = l >> 4;
    const int wr = (w >> 1) * 64, wc = (w & 1) * 64;
    f32x4 acc[4][4] = {};
    const char* gA = (const char*)xb + (long long)(m0 + (t>>3))*2048 + (t&7)*16;
    const char* gB = (const char*)wt + (long long)(n0 + (t>>3))*2048 + (t&7)*16;
    char* lAp = (char*)lA + t*16;
    char* lBp = (char*)lB + t*16;
    for (int k0 = 0; k0 < 1024; k0 += 64) {
        #pragma unroll
        for (int i = 0; i < 4; ++i) {
            gload16(gA + (long long)i*32*2048, lAp + i*4096);
            gload16(gB + (long long)i*32*2048, lBp + i*4096);
        }
        gA += 128; gB += 128;
        __syncthreads();
        #pragma unroll
        for (int kk = 0; kk < 2; ++kk) {
            bf16x8 af[4], bfr[4];
            #pragma unroll
            for (int mi = 0; mi < 4; ++mi)
                af[mi] = *(const bf16x8*)((const char*)lA + (wr + mi*16 + lm)*128 + kk*64 + lg*16);
            #pragma unroll
            for (int ni = 0; ni < 4; ++ni)
                bfr[ni] = *(const bf16x8*)((const char*)lB + (wc + ni*16 + lm)*128 + kk*64 + lg*16);
            #pragma unroll
            for (int mi = 0; mi < 4; ++mi)
                #pragma unroll
                for (int ni = 0; ni < 4; ++ni)
                    acc[mi][ni] = mfma16(bfr[ni], af[mi], acc[mi][ni]);
        }
        __syncthreads();
    }
    #pragma unroll
    for (int mi = 0; mi < 4; ++mi) {
        const int m = m0 + wr + mi*16 + lm;
        const int b = m >> 11, s = m & 2047;
        #pragma unroll
        for (int ni = 0; ni < 4; ++ni) {
            const int nb = n0 + wc + ni*16 + lg*4;
            const float4 bn4 = *(const float4*)&bias[nb];
            const int hh = nb >> 6, d = nb & 63;
            uint2 pk;
            pk.x = cvtpk(acc[mi][ni][0] + bn4.x, acc[mi][ni][1] + bn4.y);
            pk.y = cvtpk(acc[mi][ni][2] + bn4.z, acc[mi][ni][3] + bn4.w);
            *(uint2*)&out[(((long long)b*16 + hh)*2048 + s)*64 + d] = pk;
        }
    }
}

// ---------------- V [bh][s][d] -> Vt [bh][d][s] ----------------
__global__ __launch_bounds__(256) void k_vtrans(const u16* __restrict__ vb, u16* __restrict__ vt) {
    __shared__ u16 tl[64][40];
    const int t = threadIdx.x;
    const int bh = blockIdx.z, s0 = blockIdx.y*64, d0 = blockIdx.x*32;
    const u16* vsrc = vb + (long long)bh*2048*64;
    {
        const int sl = t >> 2, dg = t & 3;
        bf16x8 v = *(const bf16x8*)&vsrc[(long long)(s0+sl)*64 + d0 + dg*8];
        *(bf16x8*)&tl[sl][dg*8] = v;
    }
    __syncthreads();
    {
        const int dl = t >> 3, sg = t & 7;
        bf16x8 o;
        #pragma unroll
        for (int j = 0; j < 8; ++j) o[j] = (short)tl[sg*8+j][dl];
        *(bf16x8*)&vt[((long long)bh*64 + d0+dl)*2048 + s0 + sg*8] = o;
    }
}

// ---------------- attention pass 1: ctx + invl (round-9 exact) ----------------
__global__ __launch_bounds__(512, 4) void k_attn_ctx(const u16* __restrict__ Qb, const u16* __restrict__ Kb,
                                                     const u16* __restrict__ Vt, const float* __restrict__ qsv,
                                                     float* __restrict__ invg, u16* __restrict__ ctxb) {
    __shared__ char lds[81920];

    const int nl = blockIdx.x;
    const int ob = (nl & 7)*64 + (nl >> 3);
    const int bh = ob >> 3, qt = ob & 7;
    const int t = threadIdx.x, w = t >> 6, l = t & 63, lm = l & 15, lg = l >> 4;
    const int q0 = qt * 256;
    const float qs = qsv[bh];

    const char* KB = (const char*)Kb + (long long)bh * 262144;
    const char* VB = (const char*)Vt + (long long)bh * 262144;

    bf16x8 qf[2][2];
    {
        const char* QB = (const char*)Qb + (long long)bh * 262144;
        #pragma unroll
        for (int ms = 0; ms < 2; ++ms)
            #pragma unroll
            for (int kc = 0; kc < 2; ++kc)
                qf[ms][kc] = *(const bf16x8*)(QB + (long long)(q0 + w*32 + ms*16 + lm)*128 + kc*64 + lg*16);
    }

    const int off = t*16;
    const int row = off >> 7, cbyt = off & 127;
    const int offA = off;
    const int srcK = row*128  + (cbyt ^ ((row & 7) << 4));
    const int srcV = row*4096 + (cbyt ^ ((row & 7) << 4));

    char* lP = lds + 49152;
    float lsum[2] = {0.f, 0.f};
    f32x4 cacc[2][4] = {};

    gload16(KB + srcK, lds + offA);
    gload16(VB + srcV, lds + 24576 + offA);
    gload16(KB + 8192 + srcK, lds + 8192 + offA);
    gload16(VB + 128 + srcV, lds + 24576 + 8192 + offA);
    SCHEDB();
    WAITV(2); BAR(); SCHEDB();

    int cb_ = 0, sb_ = 2;
    for (int kt = 0; kt < 32; ++kt) {
        const int ktn = (kt < 30) ? kt + 2 : 31;
        gload16(KB + (long long)ktn*8192 + srcK, lds + sb_*8192 + offA);
        gload16(VB + (long long)ktn*128 + srcV, lds + 24576 + sb_*8192 + offA);
        SCHEDB();

        const char* kb = lds + cb_*8192;
        #pragma unroll
        for (int ns = 0; ns < 4; ++ns) {
            const int rowb = ns*16 + lm;
            const int tag = (rowb & 7) << 4;
            bf16x8 kf0 = *(const bf16x8*)(kb + rowb*128 + ((lg*16) ^ tag));
            bf16x8 kf1 = *(const bf16x8*)(kb + rowb*128 + ((64 + lg*16) ^ tag));
            #pragma unroll
            for (int ms = 0; ms < 2; ++ms) {
                f32x4 a = {};
                a = mfma16(kf0, qf[ms][0], a);
                a = mfma16(kf1, qf[ms][1], a);
                const float p0 = __expf(a[0]*qs);
                const float p1 = __expf(a[1]*qs);
                const float p2 = __expf(a[2]*qs);
                const float p3 = __expf(a[3]*qs);
                lsum[ms] += (p0 + p1) + (p2 + p3);
                const int prow = w*32 + ms*16 + lm;
                const int ptag = (prow & 7) << 4;
                uint2 pk; pk.x = cvtpk(p0, p1); pk.y = cvtpk(p2, p3);
                *(uint2*)(lP + prow*128 + ((32*ns + 8*lg) ^ ptag)) = pk;
            }
        }
        WAITL0(); SCHEDB();

        const char* vb = lds + 24576 + cb_*8192;
        #pragma unroll
        for (int ks = 0; ks < 2; ++ks) {
            bf16x8 pa[2];
            #pragma unroll
            for (int ms = 0; ms < 2; ++ms) {
                const int prow = w*32 + ms*16 + lm;
                pa[ms] = *(const bf16x8*)(lP + prow*128 + ((ks*64 + lg*16) ^ ((prow & 7) << 4)));
            }
            #pragma unroll
            for (int dn = 0; dn < 4; ++dn) {
                const int rv = dn*16 + lm;
                bf16x8 vf = *(const bf16x8*)(vb + rv*128 + ((ks*64 + lg*16) ^ ((rv & 7) << 4)));
                cacc[0][dn] = mfma16(pa[0], vf, cacc[0][dn]);
                cacc[1][dn] = mfma16(pa[1], vf, cacc[1][dn]);
            }
        }
        WAITV(2); BAR(); SCHEDB();
        cb_ = (cb_ == 2) ? 0 : cb_ + 1;
        sb_ = (sb_ == 2) ? 0 : sb_ + 1;
    }

    float invl[2];
    #pragma unroll
    for (int ms = 0; ms < 2; ++ms) {
        float v = lsum[ms];
        v += __shfl_xor(v, 16);
        v += __shfl_xor(v, 32);
        invl[ms] = 1.f / v;
    }
    if (lg == 0) {
        invg[bh*2048 + q0 + w*32 + lm]      = invl[0];
        invg[bh*2048 + q0 + w*32 + 16 + lm] = invl[1];
    }
    float* fs = (float*)(lP + w*4096);
    if (lg == 0) { fs[lm] = invl[0]; fs[16 + lm] = invl[1]; }
    WAITL0(); SCHEDB();
    f32x4 iv[2];
    iv[0] = *(const f32x4*)&fs[lg*4];
    iv[1] = *(const f32x4*)&fs[16 + lg*4];

    const int b = bh >> 4, hh = bh & 15;
    #pragma unroll
    for (int ms = 0; ms < 2; ++ms)
        #pragma unroll
        for (int dn = 0; dn < 4; ++dn)
            #pragma unroll
            for (int r = 0; r < 4; ++r) {
                const int q = q0 + w*32 + ms*16 + lg*4 + r;
                ctxb[(((long long)b*2048 + q)*16 + hh)*64 + dn*16 + lm] = f2bf(cacc[ms][dn][r] * iv[ms][r]);
            }
}

// ---------------- attention pass 2 v4: 3 blocks/CU, 512B-burst flush every 2 tiles ----------------
// LDS 48KB: K 4x8KB ring @0, P 32 rows x 512B @32768. 4096 blocks x 256 thr.
// vmcnt ladder (derived in-order, loads L2/tile, stores S4/flush):
//   kt<2: W4; kt==2: W8; kt>=3: odd->W8, even->W12. Stores get >=4 tiles slack.
__global__ __launch_bounds__(256, 3) void k_pwrite(const u16* __restrict__ Qb, const u16* __restrict__ Kb,
                                                   const float* __restrict__ qsv, const float* __restrict__ invg,
                                                   float* __restrict__ attn_out) {
    __shared__ char lds[49152];

    const int nl = blockIdx.x;
    const int ob = (nl & 7)*512 + (nl >> 3);   // XCD-chunked (4096 % 8 == 0)
    const int bh = ob >> 6, qt = ob & 63;
    const int t = threadIdx.x, w = t >> 6, l = t & 63, lm = l & 15, lg = l >> 4;
    const int q0 = qt * 32;
    const int qg = w & 1, kq = w >> 1;
    const float qs = qsv[bh];

    const char* KB = (const char*)Kb + (long long)bh * 262144;

    bf16x8 qf[2];
    {
        const char* QB = (const char*)Qb + (long long)bh * 262144;
        #pragma unroll
        for (int kc = 0; kc < 2; ++kc)
            qf[kc] = *(const bf16x8*)(QB + (long long)(q0 + qg*16 + lm)*128 + kc*64 + lg*16);
    }
    const float invq = invg[bh*2048 + q0 + qg*16 + lm];

    int offA[2], srcK[2];
    #pragma unroll
    for (int i = 0; i < 2; ++i) {
        const int off = i*4096 + t*16;
        const int row = off >> 7, cbyt = off & 127;
        offA[i] = off;
        srcK[i] = row*128 + (cbyt ^ ((row & 7) << 4));
    }

    char* lP = lds + 32768;
    const int prow = qg*16 + lm;

    // prologue: tiles 0..2 -> bufs 0..2 (6 loads)
    #pragma unroll
    for (int tt = 0; tt < 3; ++tt)
        #pragma unroll
        for (int i = 0; i < 2; ++i)
            gload16(KB + (long long)tt*8192 + srcK[i], lds + tt*8192 + offA[i]);
    SCHEDB();

    for (int kt = 0; kt < 32; ++kt) {
        // top wait: tile kt resident; stores keep >=4 tiles of slack (counted, never 0)
        if (kt < 2)            { WAITV(4); }
        else if (kt == 2)      { WAITV(8); }
        else if (kt & 1)       { WAITV(8); }
        else                   { WAITV(12); }
        BAR(); SCHEDB();

        // issue loads for tile kt+3 (buf freed at the barrier above)
        {
            const int ktn = (kt + 3 < 32) ? kt + 3 : 31;
            char* dst = lds + ((kt + 3) & 3)*8192;
            #pragma unroll
            for (int i = 0; i < 2; ++i)
                gload16(KB + (long long)ktn*8192 + srcK[i], dst + offA[i]);
        }
        SCHEDB();

        // compute tile kt: wave covers keys kq*32..+32, q-rows qg*16..+16
        const char* kb = lds + (kt & 3)*8192;
        const int tw = kt & 1;
        #pragma unroll
        for (int ns = 0; ns < 2; ++ns) {
            const int rowb = kq*32 + ns*16 + lm;
            const int tag = (lm & 7) << 4;
            bf16x8 kf0 = *(const bf16x8*)(kb + rowb*128 + ((lg*16) ^ tag));
            bf16x8 kf1 = *(const bf16x8*)(kb + rowb*128 + ((64 + lg*16) ^ tag));
            f32x4 a = {};
            a = mfma16(kf0, qf[0], a);
            a = mfma16(kf1, qf[1], a);
            f32x4 pv4;
            pv4[0] = __expf(a[0]*qs) * invq;
            pv4[1] = __expf(a[1]*qs) * invq;
            pv4[2] = __expf(a[2]*qs) * invq;
            pv4[3] = __expf(a[3]*qs) * invq;
            const int wb = (tw << 8) + (kq << 7) + (ns << 6) + (lg << 4);
            *(f32x4*)(lP + prow*512 + (wb ^ ((prow & 7) << 4))) = pv4;
        }

        // flush every 2 tiles: 32 rows x 512B; per instr 2 rows x 512B contiguous
        if (tw == 1) {
            const int win = kt >> 1;
            WAITL0(); BAR(); SCHEDB();
            #pragma unroll
            for (int r = 0; r < 4; ++r) {
                const int rr = w*8 + r*2 + (l >> 5);
                const int c16 = l & 31;
                f32x4 v = *(const f32x4*)(lP + rr*512 + ((c16*16) ^ ((rr & 7) << 4)));
                *(f32x4*)(attn_out + ((long long)(bh*2048 + q0 + rr))*2048 + win*128 + c16*4) = v;
            }
            SCHEDB();
            // next tile's top BAR protects lP reuse (reads retired into VGPRs before stores issue)
        }
    }
}

// ---------------- output projection ----------------
__global__ __launch_bounds__(256) void k_o_gemm(const u16* __restrict__ ab, const u16* __restrict__ wt,
                                                const float* __restrict__ bo, float* __restrict__ outf) {
    __shared__ u16 lA[128*64];
    __shared__ u16 lB[128*64];
    const int t = threadIdx.x;
    const int m0 = blockIdx.y * 128, n0 = blockIdx.x * 128;
    const int w = t >> 6, l = t & 63, lm = l & 15, lg = l >> 4;
    const int wr = (w >> 1) * 64, wc = (w & 1) * 64;
    f32x4 acc[4][4] = {};
    const char* gA = (const char*)ab + (long long)(m0 + (t>>3))*2048 + (t&7)*16;
    const char* gB = (const char*)wt + (long long)(n0 + (t>>3))*2048 + (t&7)*16;
    char* lAp = (char*)lA + t*16;
    char* lBp = (char*)lB + t*16;
    for (int k0 = 0; k0 < 1024; k0 += 64) {
        #pragma unroll
        for (int i = 0; i < 4; ++i) {
            gload16(gA + (long long)i*32*2048, lAp + i*4096);
            gload16(gB + (long long)i*32*2048, lBp + i*4096);
        }
        gA += 128; gB += 128;
        __syncthreads();
        #pragma unroll
        for (int kk = 0; kk < 2; ++kk) {
            bf16x8 af[4], bfr[4];
            #pragma unroll
            for (int mi = 0; mi < 4; ++mi)
                af[mi] = *(const bf16x8*)((const char*)lA + (wr + mi*16 + lm)*128 + kk*64 + lg*16);
            #pragma unroll
            for (int ni = 0; ni < 4; ++ni)
                bfr[ni] = *(const bf16x8*)((const char*)lB + (wc + ni*16 + lm)*128 + kk*64 + lg*16);
            #pragma unroll
            for (int mi = 0; mi < 4; ++mi)
                #pragma unroll
                for (int ni = 0; ni < 4; ++ni)
                    acc[mi][ni] = mfma16(bfr[ni], af[mi], acc[mi][ni]);
        }
        __syncthreads();
    }
    #pragma unroll
    for (int mi = 0; mi < 4; ++mi) {
        const int m = m0 + wr + mi*16 + lm;
        #pragma unroll
        for (int ni = 0; ni < 4; ++ni) {
            const int nb = n0 + wc + ni*16 + lg*4;
            const float4 bn4 = *(const float4*)&bo[nb];
            f32x4 v = acc[mi][ni];
            v[0] += bn4.x; v[1] += bn4.y; v[2] += bn4.z; v[3] += bn4.w;
            *(f32x4*)&outf[(long long)m*1024 + nb] = v;
        }
    }
}

extern "C" void kernel_launch(void* const* d_in, const int* in_sizes, int n_in,
                              void* d_out, int out_size, void* d_ws, size_t ws_size,
                              hipStream_t stream) {
    const float* x    = (const float*)d_in[0];
    const float* geo  = (const float*)d_in[1];
    const float* Wq   = (const float*)d_in[2];
    const float* bq   = (const float*)d_in[3];
    const float* Wk   = (const float*)d_in[4];
    const float* bk   = (const float*)d_in[5];
    const float* Wv   = (const float*)d_in[6];
    const float* bv   = (const float*)d_in[7];
    const float* Wo   = (const float*)d_in[8];
    const float* bo   = (const float*)d_in[9];
    const float* geW1 = (const float*)d_in[10];
    const float* geb1 = (const float*)d_in[11];
    const float* lng  = (const float*)d_in[12];
    const float* lnb  = (const float*)d_in[13];
    const float* geW2 = (const float*)d_in[14];
    const float* geb2 = (const float*)d_in[15];
    const float* gmW  = (const float*)d_in[16];
    const float* gmb  = (const float*)d_in[17];

    char* ws = (char*)d_ws;
    u16* xb   = (u16*)(ws + 0);                 // 16 MB (dead after k_qkv_gemm)
    u16* wt   = (u16*)(ws + 16*(size_t)MB);     // 4 x 2 MB
    u16* qkv  = (u16*)(ws + 24*(size_t)MB);     // Q,K,V each 16 MB
    u16* Qb   = qkv;
    u16* Kb   = (u16*)(ws + 40*(size_t)MB);
    u16* Vb   = (u16*)(ws + 56*(size_t)MB);
    u16* Vt   = (u16*)(ws + 72*(size_t)MB);
    u16* ctx  = Vb;                              // reuse V-raw after transpose
    float* qsb= (float*)(ws + 88*(size_t)MB);
    float* hr = (float*)(ws + 88*(size_t)MB + 4096);
    float* ge = (float*)(ws + 88*(size_t)MB + 65536);
    float* invg = (float*)(ws + 0);              // reuse xb region (dead by k_attn_ctx)

    float* outf = (float*)d_out;
    float* attn = outf + 8388608;

    hipLaunchKernelGGL(k_cvtx,     dim3(4096),      dim3(256),  0, stream, x, xb);
    hipLaunchKernelGGL(k_wtcvt,    dim3(32,32,4),   dim3(256),  0, stream, Wq, Wk, Wv, Wo, wt);
    hipLaunchKernelGGL(k_geo1,     dim3(4),         dim3(1024), 0, stream, geo, geW1, geb1, lng, lnb, hr);
    hipLaunchKernelGGL(k_geo2,     dim3(64),        dim3(256),  0, stream, hr, geW2, geb2, ge);
    hipLaunchKernelGGL(k_geo3,     dim3(1),         dim3(1024), 0, stream, ge, gmW, gmb, qsb);
    hipLaunchKernelGGL(k_qkv_gemm, dim3(8,64,3),    dim3(256),  0, stream, xb, wt, bq, bk, bv, qkv);
    hipLaunchKernelGGL(k_vtrans,   dim3(2,32,64),   dim3(256),  0, stream, Vb, Vt);
    hipLaunchKernelGGL(k_attn_ctx, dim3(512),       dim3(512),  0, stream, Qb, Kb, Vt, qsb, invg, ctx);
    hipLaunchKernelGGL(k_pwrite,   dim3(4096),      dim3(256),  0, stream, Qb, Kb, qsb, invg, attn);
    hipLaunchKernelGGL(k_o_gemm,   dim3(8,64),      dim3(256),  0, stream, ctx, wt + 3*1048576, bo, outf);
}

// Round 13
// 533.891 us; speedup vs baseline: 2.3036x; 1.0282x over previous
//
#include <hip/hip_runtime.h>

typedef __attribute__((ext_vector_type(8))) short bf16x8;
typedef __attribute__((ext_vector_type(4))) float f32x4;
typedef __attribute__((ext_vector_type(4))) unsigned short us4;
typedef unsigned short u16;

#define MB (1024*1024)

#define WAITV(N) asm volatile("s_waitcnt vmcnt(" #N ")" ::: "memory")
#define WAITL0() asm volatile("s_waitcnt lgkmcnt(0)" ::: "memory")
#define BAR()    __builtin_amdgcn_s_barrier()
#define SCHEDB() __builtin_amdgcn_sched_barrier(0)

__device__ __forceinline__ u16 f2bf(float f) {
    unsigned u = __float_as_uint(f);
    unsigned r = (u + 0x7fffu + ((u >> 16) & 1u)) >> 16;
    return (u16)r;
}

__device__ __forceinline__ unsigned cvtpk(float a, float b) {
    unsigned r;
    asm("v_cvt_pk_bf16_f32 %0, %1, %2" : "=v"(r) : "v"(a), "v"(b));
    return r;
}

__device__ __forceinline__ f32x4 mfma16(bf16x8 a, bf16x8 b, f32x4 c) {
    return __builtin_amdgcn_mfma_f32_16x16x32_bf16(a, b, c, 0, 0, 0);
}

__device__ __forceinline__ void gload16(const void* g, void* l) {
    __builtin_amdgcn_global_load_lds(
        (__attribute__((address_space(1))) void*)(unsigned long long)g,
        (__attribute__((address_space(3))) void*)l, 16, 0, 0);
}

// ---------------- x -> bf16 ----------------
__global__ __launch_bounds__(256) void k_cvtx(const float* __restrict__ x, u16* __restrict__ xb) {
    const long long i = (long long)blockIdx.x * 256 + threadIdx.x;
    const float4* xp = (const float4*)x;
    float4 a = xp[i*2], b = xp[i*2+1];
    bf16x8 o;
    o[0]=(short)f2bf(a.x); o[1]=(short)f2bf(a.y); o[2]=(short)f2bf(a.z); o[3]=(short)f2bf(a.w);
    o[4]=(short)f2bf(b.x); o[5]=(short)f2bf(b.y); o[6]=(short)f2bf(b.z); o[7]=(short)f2bf(b.w);
    *(bf16x8*)&xb[i*8] = o;
}

// ---------------- W (K x N) -> Wt bf16 (N x K) ----------------
__global__ __launch_bounds__(256) void k_wtcvt(const float* __restrict__ W0, const float* __restrict__ W1,
                                               const float* __restrict__ W2, const float* __restrict__ W3,
                                               u16* __restrict__ wt) {
    __shared__ float tl[32][33];
    const int t = threadIdx.x, z = blockIdx.z;
    const float* W = (z==0)?W0:(z==1)?W1:(z==2)?W2:W3;
    const int k0 = blockIdx.x*32, n0 = blockIdx.y*32;
    const int r = t >> 3, c4 = (t & 7) * 4;
    float4 v = *(const float4*)&W[(long long)(k0+r)*1024 + n0 + c4];
    tl[r][c4] = v.x; tl[r][c4+1] = v.y; tl[r][c4+2] = v.z; tl[r][c4+3] = v.w;
    __syncthreads();
    us4 ov;
    ov[0] = f2bf(tl[c4+0][r]); ov[1] = f2bf(tl[c4+1][r]);
    ov[2] = f2bf(tl[c4+2][r]); ov[3] = f2bf(tl[c4+3][r]);
    *(us4*)&wt[((long long)z << 20) + (long long)(n0+r)*1024 + k0 + c4] = ov;
}

// ---------------- geo chain ----------------
__global__ __launch_bounds__(1024) void k_geo1(const float* __restrict__ geo, const float* __restrict__ W1,
                                               const float* __restrict__ b1, const float* __restrict__ lng,
                                               const float* __restrict__ lnb, float* __restrict__ hr) {
    const int b = blockIdx.x, j = threadIdx.x;
    float acc = b1[j];
    #pragma unroll 8
    for (int g = 0; g < 32; ++g) acc += geo[b*32+g] * W1[(long long)g*1024 + j];
    float s1 = acc, s2 = acc*acc;
    #pragma unroll
    for (int m = 1; m < 64; m <<= 1) { s1 += __shfl_xor(s1, m); s2 += __shfl_xor(s2, m); }
    __shared__ float r1[16], r2[16];
    __shared__ float mu_s, rv_s;
    const int wid = j >> 6, lid = j & 63;
    if (lid == 0) { r1[wid] = s1; r2[wid] = s2; }
    __syncthreads();
    if (j == 0) {
        float S1 = 0.f, S2 = 0.f;
        for (int i = 0; i < 16; ++i) { S1 += r1[i]; S2 += r2[i]; }
        float mu = S1 / 1024.f;
        float var = S2 / 1024.f - mu*mu;
        mu_s = mu; rv_s = rsqrtf(var + 1e-5f);
    }
    __syncthreads();
    float hv = (acc - mu_s) * rv_s * lng[j] + lnb[j];
    hr[b*1024 + j] = fmaxf(hv, 0.f);
}

__global__ __launch_bounds__(256) void k_geo2(const float* __restrict__ hr, const float* __restrict__ W2,
                                              const float* __restrict__ b2, float* __restrict__ ge) {
    const int b = blockIdx.x >> 4, jc = blockIdx.x & 15;
    const int t = threadIdx.x;
    __shared__ float hs[1024];
    __shared__ float parts[4][64];
    #pragma unroll
    for (int i = 0; i < 4; ++i) hs[t*4 + i] = hr[b*1024 + t*4 + i];
    __syncthreads();
    const int j = jc*64 + (t & 63), dq = t >> 6;
    float acc = 0.f;
    #pragma unroll 16
    for (int dd = 0; dd < 256; ++dd) {
        const int d = dq*256 + dd;
        acc += hs[d] * W2[(long long)d*1024 + j];
    }
    parts[dq][t & 63] = acc;
    __syncthreads();
    if (t < 64) {
        const int jj = jc*64 + t;
        ge[b*1024 + jj] = b2[jj] + parts[0][t] + parts[1][t] + parts[2][t] + parts[3][t];
    }
}

__global__ __launch_bounds__(1024) void k_geo3(const float* __restrict__ ge, const float* __restrict__ gmW,
                                               const float* __restrict__ gmb, float* __restrict__ qs) {
    const int t = threadIdx.x;
    const int hh = t & 15, b = (t >> 4) & 3, dq = t >> 6;
    __shared__ float parts[16][64];
    float part = 0.f;
    #pragma unroll 16
    for (int dd = 0; dd < 64; ++dd) {
        const int d = dq*64 + dd;
        part += ge[b*1024 + d] * gmW[d*16 + hh];
    }
    parts[dq][b*16 + hh] = part;
    __syncthreads();
    if (t < 64) {
        float s = gmb[t & 15];
        #pragma unroll
        for (int k = 0; k < 16; ++k) s += parts[k][t];
        qs[t] = 0.125f * (1.f + 1.f/(1.f + __expf(-s)));
    }
}

// ---------------- QKV projection GEMM (z folded into x for A-tile L2 locality) ----------------
__global__ __launch_bounds__(256) void k_qkv_gemm(const u16* __restrict__ xb, const u16* __restrict__ wtq,
                                                  const float* __restrict__ bq, const float* __restrict__ bk,
                                                  const float* __restrict__ bv, u16* __restrict__ outq) {
    __shared__ u16 lA[128*64];
    __shared__ u16 lB[128*64];
    const int t = threadIdx.x;
    const int zn = blockIdx.x;          // 24 = 3 z x 8 n; consecutive blocks share the A-tile
    const int z = zn % 3;
    const int m0 = blockIdx.y * 128, n0 = (zn / 3) * 128;
    const u16* wt = wtq + (long long)z * (1024*1024);
    const float* bias = (z==0) ? bq : (z==1) ? bk : bv;
    u16* out = outq + (long long)z * 8388608;
    const int w = t >> 6, l = t & 63, lm = l & 15, lg = l >> 4;
    const int wr = (w >> 1) * 64, wc = (w & 1) * 64;
    f32x4 acc[4][4] = {};
    const char* gA = (const char*)xb + (long long)(m0 + (t>>3))*2048 + (t&7)*16;
    const char* gB = (const char*)wt + (long long)(n0 + (t>>3))*2048 + (t&7)*16;
    char* lAp = (char*)lA + t*16;
    char* lBp = (char*)lB + t*16;
    for (int k0 = 0; k0 < 1024; k0 += 64) {
        #pragma unroll
        for (int i = 0; i < 4; ++i) {
            gload16(gA + (long long)i*32*2048, lAp + i*4096);
            gload16(gB + (long long)i*32*2048, lBp + i*4096);
        }
        gA += 128; gB += 128;
        __syncthreads();
        #pragma unroll
        for (int kk = 0; kk < 2; ++kk) {
            bf16x8 af[4], bfr[4];
            #pragma unroll
            for (int mi = 0; mi < 4; ++mi)
                af[mi] = *(const bf16x8*)((const char*)lA + (wr + mi*16 + lm)*128 + kk*64 + lg*16);
            #pragma unroll
            for (int ni = 0; ni < 4; ++ni)
                bfr[ni] = *(const bf16x8*)((const char*)lB + (wc + ni*16 + lm)*128 + kk*64 + lg*16);
            #pragma unroll
            for (int mi = 0; mi < 4; ++mi)
                #pragma unroll
                for (int ni = 0; ni < 4; ++ni)
                    acc[mi][ni] = mfma16(bfr[ni], af[mi], acc[mi][ni]);
        }
        __syncthreads();
    }
    #pragma unroll
    for (int mi = 0; mi < 4; ++mi) {
        const int m = m0 + wr + mi*16 + lm;
        const int b = m >> 11, s = m & 2047;
        #pragma unroll
        for (int ni = 0; ni < 4; ++ni) {
            const int nb = n0 + wc + ni*16 + lg*4;
            const float4 bn4 = *(const float4*)&bias[nb];
            const int hh = nb >> 6, d = nb & 63;
            uint2 pk;
            pk.x = cvtpk(acc[mi][ni][0] + bn4.x, acc[mi][ni][1] + bn4.y);
            pk.y = cvtpk(acc[mi][ni][2] + bn4.z, acc[mi][ni][3] + bn4.w);
            *(uint2*)&out[(((long long)b*16 + hh)*2048 + s)*64 + d] = pk;
        }
    }
}

// ---------------- V [bh][s][d] -> Vt [bh][d][s] ----------------
__global__ __launch_bounds__(256) void k_vtrans(const u16* __restrict__ vb, u16* __restrict__ vt) {
    __shared__ u16 tl[64][40];
    const int t = threadIdx.x;
    const int bh = blockIdx.z, s0 = blockIdx.y*64, d0 = blockIdx.x*32;
    const u16* vsrc = vb + (long long)bh*2048*64;
    {
        const int sl = t >> 2, dg = t & 3;
        bf16x8 v = *(const bf16x8*)&vsrc[(long long)(s0+sl)*64 + d0 + dg*8];
        *(bf16x8*)&tl[sl][dg*8] = v;
    }
    __syncthreads();
    {
        const int dl = t >> 3, sg = t & 7;
        bf16x8 o;
        #pragma unroll
        for (int j = 0; j < 8; ++j) o[j] = (short)tl[sg*8+j][dl];
        *(bf16x8*)&vt[((long long)bh*64 + d0+dl)*2048 + s0 + sg*8] = o;
    }
}

// ---------------- attention pass 1: ctx + invl (round-9 exact) ----------------
__global__ __launch_bounds__(512, 4) void k_attn_ctx(const u16* __restrict__ Qb, const u16* __restrict__ Kb,
                                                     const u16* __restrict__ Vt, const float* __restrict__ qsv,
                                                     float* __restrict__ invg, u16* __restrict__ ctxb) {
    __shared__ char lds[81920];

    const int nl = blockIdx.x;
    const int ob = (nl & 7)*64 + (nl >> 3);
    const int bh = ob >> 3, qt = ob & 7;
    const int t = threadIdx.x, w = t >> 6, l = t & 63, lm = l & 15, lg = l >> 4;
    const int q0 = qt * 256;
    const float qs = qsv[bh];

    const char* KB = (const char*)Kb + (long long)bh * 262144;
    const char* VB = (const char*)Vt + (long long)bh * 262144;

    bf16x8 qf[2][2];
    {
        const char* QB = (const char*)Qb + (long long)bh * 262144;
        #pragma unroll
        for (int ms = 0; ms < 2; ++ms)
            #pragma unroll
            for (int kc = 0; kc < 2; ++kc)
                qf[ms][kc] = *(const bf16x8*)(QB + (long long)(q0 + w*32 + ms*16 + lm)*128 + kc*64 + lg*16);
    }

    const int off = t*16;
    const int row = off >> 7, cbyt = off & 127;
    const int offA = off;
    const int srcK = row*128  + (cbyt ^ ((row & 7) << 4));
    const int srcV = row*4096 + (cbyt ^ ((row & 7) << 4));

    char* lP = lds + 49152;
    float lsum[2] = {0.f, 0.f};
    f32x4 cacc[2][4] = {};

    gload16(KB + srcK, lds + offA);
    gload16(VB + srcV, lds + 24576 + offA);
    gload16(KB + 8192 + srcK, lds + 8192 + offA);
    gload16(VB + 128 + srcV, lds + 24576 + 8192 + offA);
    SCHEDB();
    WAITV(2); BAR(); SCHEDB();

    int cb_ = 0, sb_ = 2;
    for (int kt = 0; kt < 32; ++kt) {
        const int ktn = (kt < 30) ? kt + 2 : 31;
        gload16(KB + (long long)ktn*8192 + srcK, lds + sb_*8192 + offA);
        gload16(VB + (long long)ktn*128 + srcV, lds + 24576 + sb_*8192 + offA);
        SCHEDB();

        const char* kb = lds + cb_*8192;
        #pragma unroll
        for (int ns = 0; ns < 4; ++ns) {
            const int rowb = ns*16 + lm;
            const int tag = (rowb & 7) << 4;
            bf16x8 kf0 = *(const bf16x8*)(kb + rowb*128 + ((lg*16) ^ tag));
            bf16x8 kf1 = *(const bf16x8*)(kb + rowb*128 + ((64 + lg*16) ^ tag));
            #pragma unroll
            for (int ms = 0; ms < 2; ++ms) {
                f32x4 a = {};
                a = mfma16(kf0, qf[ms][0], a);
                a = mfma16(kf1, qf[ms][1], a);
                const float p0 = __expf(a[0]*qs);
                const float p1 = __expf(a[1]*qs);
                const float p2 = __expf(a[2]*qs);
                const float p3 = __expf(a[3]*qs);
                lsum[ms] += (p0 + p1) + (p2 + p3);
                const int prow = w*32 + ms*16 + lm;
                const int ptag = (prow & 7) << 4;
                uint2 pk; pk.x = cvtpk(p0, p1); pk.y = cvtpk(p2, p3);
                *(uint2*)(lP + prow*128 + ((32*ns + 8*lg) ^ ptag)) = pk;
            }
        }
        WAITL0(); SCHEDB();

        const char* vb = lds + 24576 + cb_*8192;
        #pragma unroll
        for (int ks = 0; ks < 2; ++ks) {
            bf16x8 pa[2];
            #pragma unroll
            for (int ms = 0; ms < 2; ++ms) {
                const int prow = w*32 + ms*16 + lm;
                pa[ms] = *(const bf16x8*)(lP + prow*128 + ((ks*64 + lg*16) ^ ((prow & 7) << 4)));
            }
            #pragma unroll
            for (int dn = 0; dn < 4; ++dn) {
                const int rv = dn*16 + lm;
                bf16x8 vf = *(const bf16x8*)(vb + rv*128 + ((ks*64 + lg*16) ^ ((rv & 7) << 4)));
                cacc[0][dn] = mfma16(pa[0], vf, cacc[0][dn]);
                cacc[1][dn] = mfma16(pa[1], vf, cacc[1][dn]);
            }
        }
        WAITV(2); BAR(); SCHEDB();
        cb_ = (cb_ == 2) ? 0 : cb_ + 1;
        sb_ = (sb_ == 2) ? 0 : sb_ + 1;
    }

    float invl[2];
    #pragma unroll
    for (int ms = 0; ms < 2; ++ms) {
        float v = lsum[ms];
        v += __shfl_xor(v, 16);
        v += __shfl_xor(v, 32);
        invl[ms] = 1.f / v;
    }
    if (lg == 0) {
        invg[bh*2048 + q0 + w*32 + lm]      = invl[0];
        invg[bh*2048 + q0 + w*32 + 16 + lm] = invl[1];
    }
    float* fs = (float*)(lP + w*4096);
    if (lg == 0) { fs[lm] = invl[0]; fs[16 + lm] = invl[1]; }
    WAITL0(); SCHEDB();
    f32x4 iv[2];
    iv[0] = *(const f32x4*)&fs[lg*4];
    iv[1] = *(const f32x4*)&fs[16 + lg*4];

    const int b = bh >> 4, hh = bh & 15;
    #pragma unroll
    for (int ms = 0; ms < 2; ++ms)
        #pragma unroll
        for (int dn = 0; dn < 4; ++dn)
            #pragma unroll
            for (int r = 0; r < 4; ++r) {
                const int q = q0 + w*32 + ms*16 + lg*4 + r;
                ctxb[(((long long)b*2048 + q)*16 + hh)*64 + dn*16 + lm] = f2bf(cacc[ms][dn][r] * iv[ms][r]);
            }
}

// ---------------- attention pass 2 v3 (round-9 best; kt==4 wait corrected) ----------------
__global__ __launch_bounds__(256, 2) void k_pwrite(const u16* __restrict__ Qb, const u16* __restrict__ Kb,
                                                   const float* __restrict__ qsv, const float* __restrict__ invg,
                                                   float* __restrict__ attn_out) {
    __shared__ char lds[81920];

    const int nl = blockIdx.x;
    const int ob = (nl & 7)*512 + (nl >> 3);   // XCD-chunked (4096 % 8 == 0)
    const int bh = ob >> 6, qt = ob & 63;
    const int t = threadIdx.x, w = t >> 6, l = t & 63, lm = l & 15, lg = l >> 4;
    const int q0 = qt * 32;
    const int qg = w & 1, kq = w >> 1;
    const float qs = qsv[bh];

    const char* KB = (const char*)Kb + (long long)bh * 262144;

    bf16x8 qf[2];
    {
        const char* QB = (const char*)Qb + (long long)bh * 262144;
        #pragma unroll
        for (int kc = 0; kc < 2; ++kc)
            qf[kc] = *(const bf16x8*)(QB + (long long)(q0 + qg*16 + lm)*128 + kc*64 + lg*16);
    }
    const float invq = invg[bh*2048 + q0 + qg*16 + lm];

    int offA[2], srcK[2];
    #pragma unroll
    for (int i = 0; i < 2; ++i) {
        const int off = i*4096 + t*16;
        const int row = off >> 7, cbyt = off & 127;
        offA[i] = off;
        srcK[i] = row*128 + (cbyt ^ ((row & 7) << 4));
    }

    char* lP = lds + 49152;

    // prologue: tiles 0..4 into bufs 0..4 (10 loads)
    #pragma unroll
    for (int tt = 0; tt < 5; ++tt)
        #pragma unroll
        for (int i = 0; i < 2; ++i)
            gload16(KB + (long long)tt*8192 + srcK[i], lds + tt*8192 + offA[i]);
    SCHEDB();

    for (int kt = 0; kt < 32; ++kt) {
        // top wait: tile kt resident; stores keep in-flight slack (counted, never 0)
        if (kt < 4)              { WAITV(8); }
        else if (kt == 4)        { WAITV(16); }
        else if ((kt & 3) == 0)  { WAITV(24); }
        else                     { WAITV(16); }
        BAR(); SCHEDB();

        // issue load for tile kt+5 (target buf (kt+5)%6 freed by the barrier above)
        {
            const int ktn = (kt + 5 < 32) ? kt + 5 : 31;
            char* dst = lds + ((kt + 5) % 6)*8192;
            #pragma unroll
            for (int i = 0; i < 2; ++i)
                gload16(KB + (long long)ktn*8192 + srcK[i], dst + offA[i]);
        }
        SCHEDB();

        // compute tile kt: wave covers keys kq*32..+32, q-rows qg*16..+16
        const char* kb = lds + (kt % 6)*8192;
        #pragma unroll
        for (int ns = 0; ns < 2; ++ns) {
            const int rowb = kq*32 + ns*16 + lm;
            const int tag = (lm & 7) << 4;
            bf16x8 kf0 = *(const bf16x8*)(kb + rowb*128 + ((lg*16) ^ tag));
            bf16x8 kf1 = *(const bf16x8*)(kb + rowb*128 + ((64 + lg*16) ^ tag));
            f32x4 a = {};
            a = mfma16(kf0, qf[0], a);
            a = mfma16(kf1, qf[1], a);
            f32x4 pv4;
            pv4[0] = __expf(a[0]*qs) * invq;
            pv4[1] = __expf(a[1]*qs) * invq;
            pv4[2] = __expf(a[2]*qs) * invq;
            pv4[3] = __expf(a[3]*qs) * invq;
            const int prow = qg*16 + lm;
            const int kwb = ((kt & 3) << 8) + (kq << 7) + (ns << 6) + (lg << 4);
            *(f32x4*)(lP + prow*1024 + (kwb ^ (lm << 4))) = pv4;
        }

        // flush every 4 tiles: whole 32KB P buffer, 1KB contiguous per instruction
        if ((kt & 3) == 3) {
            const int win = kt >> 2;
            WAITL0(); BAR(); SCHEDB();
            const int r0 = w*8;
            #pragma unroll
            for (int r = 0; r < 8; ++r) {
                const int rr = r0 + r;
                f32x4 v = *(const f32x4*)(lP + rr*1024 + ((l*16) ^ ((rr & 15) << 4)));
                *(f32x4*)(attn_out + ((long long)(bh*2048 + q0 + rr))*2048 + win*256 + l*4) = v;
            }
            SCHEDB();
            // next tile's top BAR protects lP reuse (reads retired into VGPRs before stores issue)
        }
    }
}

// ---------------- output projection ----------------
__global__ __launch_bounds__(256) void k_o_gemm(const u16* __restrict__ ab, const u16* __restrict__ wt,
                                                const float* __restrict__ bo, float* __restrict__ outf) {
    __shared__ u16 lA[128*64];
    __shared__ u16 lB[128*64];
    const int t = threadIdx.x;
    const int m0 = blockIdx.y * 128, n0 = blockIdx.x * 128;
    const int w = t >> 6, l = t & 63, lm = l & 15, lg = l >> 4;
    const int wr = (w >> 1) * 64, wc = (w & 1) * 64;
    f32x4 acc[4][4] = {};
    const char* gA = (const char*)ab + (long long)(m0 + (t>>3))*2048 + (t&7)*16;
    const char* gB = (const char*)wt + (long long)(n0 + (t>>3))*2048 + (t&7)*16;
    char* lAp = (char*)lA + t*16;
    char* lBp = (char*)lB + t*16;
    for (int k0 = 0; k0 < 1024; k0 += 64) {
        #pragma unroll
        for (int i = 0; i < 4; ++i) {
            gload16(gA + (long long)i*32*2048, lAp + i*4096);
            gload16(gB + (long long)i*32*2048, lBp + i*4096);
        }
        gA += 128; gB += 128;
        __syncthreads();
        #pragma unroll
        for (int kk = 0; kk < 2; ++kk) {
            bf16x8 af[4], bfr[4];
            #pragma unroll
            for (int mi = 0; mi < 4; ++mi)
                af[mi] = *(const bf16x8*)((const char*)lA + (wr + mi*16 + lm)*128 + kk*64 + lg*16);
            #pragma unroll
            for (int ni = 0; ni < 4; ++ni)
                bfr[ni] = *(const bf16x8*)((const char*)lB + (wc + ni*16 + lm)*128 + kk*64 + lg*16);
            #pragma unroll
            for (int mi = 0; mi < 4; ++mi)
                #pragma unroll
                for (int ni = 0; ni < 4; ++ni)
                    acc[mi][ni] = mfma16(bfr[ni], af[mi], acc[mi][ni]);
        }
        __syncthreads();
    }
    #pragma unroll
    for (int mi = 0; mi < 4; ++mi) {
        const int m = m0 + wr + mi*16 + lm;
        #pragma unroll
        for (int ni = 0; ni < 4; ++ni) {
            const int nb = n0 + wc + ni*16 + lg*4;
            const float4 bn4 = *(const float4*)&bo[nb];
            f32x4 v = acc[mi][ni];
            v[0] += bn4.x; v[1] += bn4.y; v[2] += bn4.z; v[3] += bn4.w;
            *(f32x4*)&outf[(long long)m*1024 + nb] = v;
        }
    }
}

extern "C" void kernel_launch(void* const* d_in, const int* in_sizes, int n_in,
                              void* d_out, int out_size, void* d_ws, size_t ws_size,
                              hipStream_t stream) {
    const float* x    = (const float*)d_in[0];
    const float* geo  = (const float*)d_in[1];
    const float* Wq   = (const float*)d_in[2];
    const float* bq   = (const float*)d_in[3];
    const float* Wk   = (const float*)d_in[4];
    const float* bk   = (const float*)d_in[5];
    const float* Wv   = (const float*)d_in[6];
    const float* bv   = (const float*)d_in[7];
    const float* Wo   = (const float*)d_in[8];
    const float* bo   = (const float*)d_in[9];
    const float* geW1 = (const float*)d_in[10];
    const float* geb1 = (const float*)d_in[11];
    const float* lng  = (const float*)d_in[12];
    const float* lnb  = (const float*)d_in[13];
    const float* geW2 = (const float*)d_in[14];
    const float* geb2 = (const float*)d_in[15];
    const float* gmW  = (const float*)d_in[16];
    const float* gmb  = (const float*)d_in[17];

    char* ws = (char*)d_ws;
    u16* xb   = (u16*)(ws + 0);                 // 16 MB (dead after k_qkv_gemm)
    u16* wt   = (u16*)(ws + 16*(size_t)MB);     // 4 x 2 MB
    u16* qkv  = (u16*)(ws + 24*(size_t)MB);     // Q,K,V each 16 MB
    u16* Qb   = qkv;
    u16* Kb   = (u16*)(ws + 40*(size_t)MB);
    u16* Vb   = (u16*)(ws + 56*(size_t)MB);
    u16* Vt   = (u16*)(ws + 72*(size_t)MB);
    u16* ctx  = Vb;                              // reuse V-raw after transpose
    float* qsb= (float*)(ws + 88*(size_t)MB);
    float* hr = (float*)(ws + 88*(size_t)MB + 4096);
    float* ge = (float*)(ws + 88*(size_t)MB + 65536);
    float* invg = (float*)(ws + 0);              // reuse xb region (dead by k_attn_ctx)

    float* outf = (float*)d_out;
    float* attn = outf + 8388608;

    hipLaunchKernelGGL(k_cvtx,     dim3(4096),      dim3(256),  0, stream, x, xb);
    hipLaunchKernelGGL(k_wtcvt,    dim3(32,32,4),   dim3(256),  0, stream, Wq, Wk, Wv, Wo, wt);
    hipLaunchKernelGGL(k_geo1,     dim3(4),         dim3(1024), 0, stream, geo, geW1, geb1, lng, lnb, hr);
    hipLaunchKernelGGL(k_geo2,     dim3(64),        dim3(256),  0, stream, hr, geW2, geb2, ge);
    hipLaunchKernelGGL(k_geo3,     dim3(1),         dim3(1024), 0, stream, ge, gmW, gmb, qsb);
    hipLaunchKernelGGL(k_qkv_gemm, dim3(24,64),     dim3(256),  0, stream, xb, wt, bq, bk, bv, qkv);
    hipLaunchKernelGGL(k_vtrans,   dim3(2,32,64),   dim3(256),  0, stream, Vb, Vt);
    hipLaunchKernelGGL(k_attn_ctx, dim3(512),       dim3(512),  0, stream, Qb, Kb, Vt, qsb, invg, ctx);
    hipLaunchKernelGGL(k_pwrite,   dim3(4096),      dim3(256),  0, stream, Qb, Kb, qsb, invg, attn);
    hipLaunchKernelGGL(k_o_gemm,   dim3(8,64),      dim3(256),  0, stream, ctx, wt + 3*1048576, bo, outf);
}